// Round 1
// baseline (67.824 us; speedup 1.0000x reference)
//
#include <hip/hip_runtime.h>

// DOF6Loss: loss = mean((100*(±p0[:,0:3] - t[:,0:3]))^2) + mean((1000*(±p0[:,3:6] - t[:,3:6]))^2)
// where sign flip per-element depends on p1n = (p1+EPS)/max(||p1+EPS||, 1e-12) < 0.5,
// norm over the full K=4096 row of p1 = prediction[:,1,:].
//
// Memory-bound: must read all of p1 (64 MB); p0/target contribute only 6 elems/row.

#define EPS 1e-9f
#define NORM_EPS 1e-12f

__global__ __launch_bounds__(256) void dof6_loss_kernel(
    const float* __restrict__ pred,   // (B, 2, K) f32
    const float* __restrict__ targ,   // (B, 2, K) f32
    float* __restrict__ out,          // scalar f32
    int K, float inv3B)
{
    const int b = blockIdx.x;
    const size_t row_base = (size_t)b * 2 * (size_t)K;
    const float* __restrict__ p1 = pred + row_base + K;

    // --- sum of squares of (p1 + EPS) over the row, float4-vectorized ---
    float ss = 0.f;
    const float4* __restrict__ p1v = (const float4*)p1;
    const int nv = K >> 2;                       // K/4 float4 chunks
    for (int i = threadIdx.x; i < nv; i += blockDim.x) {
        float4 v = p1v[i];
        float a0 = v.x + EPS, a1 = v.y + EPS, a2 = v.z + EPS, a3 = v.w + EPS;
        ss += a0 * a0 + a1 * a1 + a2 * a2 + a3 * a3;
    }

    // --- wave (64-lane) shuffle reduce, then cross-wave via LDS ---
    #pragma unroll
    for (int off = 32; off > 0; off >>= 1)
        ss += __shfl_down(ss, off, 64);

    __shared__ float warp_ss[4];                 // 256 threads -> 4 waves
    const int lane = threadIdx.x & 63;
    const int wid  = threadIdx.x >> 6;
    if (lane == 0) warp_ss[wid] = ss;
    __syncthreads();

    if (threadIdx.x == 0) {
        float tot = warp_ss[0] + warp_ss[1] + warp_ss[2] + warp_ss[3];
        const float inv_norm = 1.0f / fmaxf(sqrtf(tot), NORM_EPS);

        const float* __restrict__ p0 = pred + row_base;       // prediction[b,0,:]
        const float* __restrict__ t0 = targ + row_base;       // target[b,0,:]

        float acc = 0.f;
        #pragma unroll
        for (int j = 0; j < 6; ++j) {
            float p0j = p0[j] + EPS;
            float p1j = p0[K + j] + EPS;         // p1[j] (same row, second plane)
            float p1n = p1j * inv_norm;
            if (p1n < 0.5f) p0j = -p0j;          // jnp.where(p1n < 0.5, -p0, p0)
            const float scale = (j < 3) ? 100.0f : 1000.0f;
            const float d = (p0j - t0[j]) * scale;
            acc += d * d;
        }
        atomicAdd(out, acc * inv3B);
    }
}

extern "C" void kernel_launch(void* const* d_in, const int* in_sizes, int n_in,
                              void* d_out, int out_size, void* d_ws, size_t ws_size,
                              hipStream_t stream) {
    const float* pred = (const float*)d_in[0];
    const float* targ = (const float*)d_in[1];
    float* out = (float*)d_out;

    const int K = 4096;                          // per reference setup_inputs
    const int B = in_sizes[0] / (2 * K);         // 4096
    const float inv3B = 1.0f / (3.0f * (float)B);

    // Zero the scalar accumulator each launch (harness poisons once, never re-poisons).
    hipMemsetAsync(d_out, 0, sizeof(float), stream);

    dof6_loss_kernel<<<B, 256, 0, stream>>>(pred, targ, out, K, inv3B);
}

// Round 2
// 19.262 us; speedup vs baseline: 3.5211x; 3.5211x over previous
//
#include <hip/hip_runtime.h>

// DOF6Loss: loss = mean((100*(±p0[:,0:3]-t[:,0:3]))^2) + mean((1000*(±p0[:,3:6]-t[:,3:6]))^2)
// sign flip per element j: (p1[j]+EPS)/max(||p1+EPS||,1e-12) < 0.5  (norm over full K row)
//
// Memory-bound on the p1 plane read (B*K floats = 64 MB). Structure:
//   k1: one wave (64 lanes) per row, 16 independent float4 loads/lane, butterfly
//       shuffle reduce, lanes 0-5 compute the 6 loss terms, block partial -> d_ws.
//   k2: single block tree-reduces the 1024 partials -> d_out (no atomics, no memset).

#define EPS 1e-9f
#define NORM_EPS 1e-12f

__global__ __launch_bounds__(256) void dof6_rows_kernel(
    const float* __restrict__ pred,   // (B, 2, K) f32
    const float* __restrict__ targ,   // (B, 2, K) f32
    float* __restrict__ partial,      // one float per block
    int K, float inv3B)
{
    const int lane = threadIdx.x & 63;
    const int wid  = threadIdx.x >> 6;              // 0..3: wave within block
    const int row  = blockIdx.x * 4 + wid;          // one row per wave
    const size_t base = (size_t)row * 2 * (size_t)K;

    // Early head loads (lanes 0..5) — issued before the stream so their
    // latency hides under the row read. Coalesced within one cache line.
    float ph = 0.f, p1h = 0.f, th = 0.f;
    if (lane < 6) {
        ph  = pred[base + lane];        // p0[j]
        p1h = pred[base + K + lane];    // p1[j]
        th  = targ[base + lane];        // target[b,0,j]
    }

    // Stream the p1 row: K floats = K/4 float4; 64 lanes -> 16 float4/lane,
    // issued as 4 independent quads per iteration (4 iterations).
    const float4* __restrict__ p1v = (const float4*)(pred + base + K);
    const int nv = K >> 2;                          // 1024
    float acc0 = 0.f, acc1 = 0.f, acc2 = 0.f, acc3 = 0.f;
    #pragma unroll
    for (int i = lane; i < nv; i += 256) {
        float4 a = p1v[i];
        float4 b = p1v[i + 64];
        float4 c = p1v[i + 128];
        float4 d = p1v[i + 192];
        float a0=a.x+EPS, a1=a.y+EPS, a2=a.z+EPS, a3=a.w+EPS;
        float b0=b.x+EPS, b1=b.y+EPS, b2=b.z+EPS, b3=b.w+EPS;
        float c0=c.x+EPS, c1=c.y+EPS, c2=c.z+EPS, c3=c.w+EPS;
        float d0=d.x+EPS, d1=d.y+EPS, d2=d.z+EPS, d3=d.w+EPS;
        acc0 += a0*a0 + a1*a1 + a2*a2 + a3*a3;
        acc1 += b0*b0 + b1*b1 + b2*b2 + b3*b3;
        acc2 += c0*c0 + c1*c1 + c2*c2 + c3*c3;
        acc3 += d0*d0 + d1*d1 + d2*d2 + d3*d3;
    }

    // Butterfly reduce across the wave — every lane ends with the row sumsq.
    float ss = (acc0 + acc1) + (acc2 + acc3);
    #pragma unroll
    for (int off = 1; off < 64; off <<= 1)
        ss += __shfl_xor(ss, off, 64);

    // Lanes 0..5 each handle one loss element; others contribute 0.
    float c = 0.f;
    if (lane < 6) {
        const float inv_norm = 1.0f / fmaxf(sqrtf(ss), NORM_EPS);
        float p0j = ph + EPS;
        const float p1n = (p1h + EPS) * inv_norm;
        if (p1n < 0.5f) p0j = -p0j;
        const float scale = (lane < 3) ? 100.0f : 1000.0f;
        const float d = (p0j - th) * scale;
        c = d * d * inv3B;
    }
    // Sum over lanes 0..7 (6,7 are zero) — 3-step butterfly.
    c += __shfl_xor(c, 1, 64);
    c += __shfl_xor(c, 2, 64);
    c += __shfl_xor(c, 4, 64);

    __shared__ float part[4];
    if (lane == 0) part[wid] = c;
    __syncthreads();
    if (threadIdx.x == 0)
        partial[blockIdx.x] = (part[0] + part[1]) + (part[2] + part[3]);
}

__global__ __launch_bounds__(256) void dof6_reduce_kernel(
    const float* __restrict__ partial, float* __restrict__ out, int n)
{
    float s = 0.f;
    for (int i = threadIdx.x; i < n; i += 256) s += partial[i];
    #pragma unroll
    for (int off = 1; off < 64; off <<= 1)
        s += __shfl_xor(s, off, 64);
    __shared__ float part[4];
    const int lane = threadIdx.x & 63, wid = threadIdx.x >> 6;
    if (lane == 0) part[wid] = s;
    __syncthreads();
    if (threadIdx.x == 0) out[0] = (part[0] + part[1]) + (part[2] + part[3]);
}

extern "C" void kernel_launch(void* const* d_in, const int* in_sizes, int n_in,
                              void* d_out, int out_size, void* d_ws, size_t ws_size,
                              hipStream_t stream) {
    const float* pred = (const float*)d_in[0];
    const float* targ = (const float*)d_in[1];
    float* out = (float*)d_out;
    float* partial = (float*)d_ws;

    const int K = 4096;                       // per reference setup_inputs
    const int B = in_sizes[0] / (2 * K);      // 4096
    const float inv3B = 1.0f / (3.0f * (float)B);
    const int nblocks = B / 4;                // one wave per row, 4 waves/block

    dof6_rows_kernel<<<nblocks, 256, 0, stream>>>(pred, targ, partial, K, inv3B);
    dof6_reduce_kernel<<<1, 256, 0, stream>>>(partial, out, nblocks);
}